// Round 2
// baseline (164.520 us; speedup 1.0000x reference)
//
#include <hip/hip_runtime.h>
#include <math.h>

#define HW 4096
#define CIN 256
#define DD 256
#define M_TOTAL 48
#define NSP 4
#define SPPX (HW / NSP)   // 1024 pixels per spatial slice (K2 z-split)

// ---------------------------------------------------------------------------
// K1 (304 blocks x 256 thr):
//   blocks 0..47    : one block per m. Flow + bilinear tap scatter for ALL
//                     4096 output pixels into a private 16 KB LDS map,
//                     written once to Ag[m][4096]. Total tap mass -> Sg[m].
//   blocks 48..303  : fold WT[ci][o] = sum_k W_dc[o,k]*W_emb[k,ci] (stored
//                     transposed), bfold[o] = W_dc[o,:].b_emb, zero out.
// ---------------------------------------------------------------------------
__global__ __launch_bounds__(256) void k_pre(
    const float* __restrict__ p_motions,
    const float* __restrict__ W_emb,
    const float* __restrict__ b_emb,
    const float* __restrict__ W_dc,
    float* __restrict__ Ag,      // [48][4096] full maps
    float* __restrict__ Sg,      // [48]
    float* __restrict__ WT,      // [256][256] = WT[ci*256+o]
    float* __restrict__ bfold,   // [256]
    float* __restrict__ out)     // zeroed here
{
    const int tid = threadIdx.x;
    const int bid = blockIdx.x;

    if (bid < M_TOTAL) {
        // ---------------- flow + scatter (whole map, one block per m) ------
        __shared__ float Al[HW];     // 16 KB private map
        __shared__ float red[4];
        const int m = bid;
        const float4* p0 = (const float4*)(p_motions + (size_t)m * 2 * 65536); // dy
        const float4* p1 = p0 + 65536 / 4;                                     // dx

        for (int i = tid; i < HW; i += 256) Al[i] = 0.f;
        __syncthreads();

        #pragma unroll 4
        for (int ii = 0; ii < HW / 256; ++ii) {
            const int i = ii * 256 + tid;          // 0..4095
            const int y = i >> 6;
            const int x = i & 63;
            const int r1 = 4 * y + 1, r2 = 4 * y + 2;
            // taps at cols 4x+1,4x+2 = elements .y/.z of float4 index x
            const float4 v10 = p0[r1 * 64 + x];
            const float4 v20 = p0[r2 * 64 + x];
            const float4 v11 = p1[r1 * 64 + x];
            const float4 v21 = p1[r2 * 64 + x];
            const float fy = (v10.y + v10.z + v20.y + v20.z) * 0.0625f; // avg*0.25
            const float fx = (v11.y + v11.z + v21.y + v21.z) * 0.0625f;

            const float yy = (float)y + fy;
            const float xx = (float)x + fx;
            const float y0f = floorf(yy), x0f = floorf(xx);
            const float wy = yy - y0f, wx = xx - x0f;
            const int iy0 = (int)y0f, ix0 = (int)x0f;
            const int iy1 = iy0 + 1, ix1 = ix0 + 1;
            const float w00 = (1.f - wy) * (1.f - wx);
            const float w01 = (1.f - wy) * wx;
            const float w10 = wy * (1.f - wx);
            const float w11 = wy * wx;
            const bool y0ok = (iy0 >= 0) & (iy0 < 64);
            const bool y1ok = (iy1 >= 0) & (iy1 < 64);
            const bool x0ok = (ix0 >= 0) & (ix0 < 64);
            const bool x1ok = (ix1 >= 0) & (ix1 < 64);
            if (y0ok & x0ok) atomicAdd(&Al[iy0 * 64 + ix0], w00);
            if (y0ok & x1ok) atomicAdd(&Al[iy0 * 64 + ix1], w01);
            if (y1ok & x0ok) atomicAdd(&Al[iy1 * 64 + ix0], w10);
            if (y1ok & x1ok) atomicAdd(&Al[iy1 * 64 + ix1], w11);
        }
        __syncthreads();

        // write whole map (plain float4 stores) + total tap mass
        const float4* Al4 = (const float4*)Al;
        float4* dst = (float4*)(Ag + (size_t)m * HW);
        float part = 0.f;
        #pragma unroll
        for (int i = tid; i < HW / 4; i += 256) {
            const float4 v = Al4[i];
            dst[i] = v;
            part += v.x + v.y + v.z + v.w;
        }
        for (int off = 32; off > 0; off >>= 1) part += __shfl_down(part, off, 64);
        if ((tid & 63) == 0) red[tid >> 6] = part;
        __syncthreads();
        if (tid == 0) Sg[m] = red[0] + red[1] + red[2] + red[3];
    } else {
        // ---------------- weight fold + out zeroing ----------------
        __shared__ float wdc[256];
        __shared__ float red2[4];
        const int o = bid - M_TOTAL;           // 0..255
        wdc[tid] = W_dc[(size_t)o * 256 + tid];
        if (tid < 48) out[(size_t)o * 48 + tid] = 0.f;  // 256*48 = 48*256 floats
        __syncthreads();
        float acc = 0.f;
        #pragma unroll 8
        for (int k = 0; k < 256; ++k)
            acc += wdc[k] * W_emb[(size_t)k * 256 + tid];   // coalesced rows
        WT[(size_t)tid * 256 + o] = acc;                    // transposed store

        float pb = wdc[tid] * b_emb[tid];
        for (int off = 32; off > 0; off >>= 1) pb += __shfl_down(pb, off, 64);
        if ((tid & 63) == 0) red2[tid >> 6] = pb;
        __syncthreads();
        if (tid == 0) bfold[o] = red2[0] + red2[1] + red2[2] + red2[3];
    }
}

// ---------------------------------------------------------------------------
// K2 v3: gather + epilogue fused. Grid (fm=16, chunk=8, sp=4) = 512 blocks.
// A maps are single (no partials) -> each wave loads its a[3][4] fragment
// straight from global (L2-hot, A = 786 KB total). No Phase-A LDS staging,
// no extra barrier, 384 B LDS. Each block covers 32 channels (8 per wave):
// stream i_features once (exactly-once HBM traffic, 67 MB), dot with the 3
// A slices, wave-reduce, apply the 32x256 WT slice, atomicAdd into out.
// ---------------------------------------------------------------------------
__global__ __launch_bounds__(256, 2) void k_gather_out(
    const float* __restrict__ i_features,
    const float* __restrict__ Ag,
    const float* __restrict__ Sg,
    const float* __restrict__ WT,
    const float* __restrict__ bfold,
    const float* __restrict__ b_dc,
    float* __restrict__ out)
{
    __shared__ float gl[3][32];
    const int fm = blockIdx.x;     // 0..15
    const int chunk = blockIdx.y;  // 0..7
    const int sp = blockIdx.z;     // 0..3
    const int tid = threadIdx.x;
    const int wave = tid >> 6, lane = tid & 63;
    const int m0 = fm * 3;

    // A fragments direct from global (coalesced float4, L2-resident)
    float4 a[3][4];
    #pragma unroll
    for (int j = 0; j < 3; ++j) {
        const float4* A4 = (const float4*)(Ag + (size_t)(m0 + j) * HW + sp * SPPX);
        #pragma unroll
        for (int k = 0; k < 4; ++k)
            a[j][k] = A4[lane + 64 * k];
    }

    // stream 32 channels of i_features (8 per wave), dot with A
    #pragma unroll 2
    for (int c = 0; c < 8; ++c) {
        const int ci = chunk * 32 + wave * 8 + c;
        const float4* f4 = (const float4*)(i_features + ((size_t)fm * CIN + ci) * HW + sp * SPPX);
        float s0 = 0.f, s1 = 0.f, s2 = 0.f;
        #pragma unroll
        for (int k = 0; k < 4; ++k) {
            const float4 v = f4[lane + 64 * k];
            s0 += v.x * a[0][k].x + v.y * a[0][k].y + v.z * a[0][k].z + v.w * a[0][k].w;
            s1 += v.x * a[1][k].x + v.y * a[1][k].y + v.z * a[1][k].z + v.w * a[1][k].w;
            s2 += v.x * a[2][k].x + v.y * a[2][k].y + v.z * a[2][k].z + v.w * a[2][k].w;
        }
        #pragma unroll
        for (int off = 32; off > 0; off >>= 1) {
            s0 += __shfl_down(s0, off, 64);
            s1 += __shfl_down(s1, off, 64);
            s2 += __shfl_down(s2, off, 64);
        }
        if (lane == 0) {
            gl[0][wave * 8 + c] = s0;
            gl[1][wave * 8 + c] = s1;
            gl[2][wave * 8 + c] = s2;
        }
    }
    __syncthreads();

    // epilogue: out[m, o] += sum_q gl[m][q] * WT[chunk*32+q, o] / 4096
    const int o = tid;
    float acc0 = 0.f, acc1 = 0.f, acc2 = 0.f;
    #pragma unroll
    for (int q = 0; q < 32; ++q) {
        const float wv = WT[(size_t)(chunk * 32 + q) * DD + o];  // coalesced
        acc0 += gl[0][q] * wv;
        acc1 += gl[1][q] * wv;
        acc2 += gl[2][q] * wv;
    }
    const float inv = 1.f / 4096.f;
    atomicAdd(&out[(size_t)(m0 + 0) * DD + o], acc0 * inv);
    atomicAdd(&out[(size_t)(m0 + 1) * DD + o], acc1 * inv);
    atomicAdd(&out[(size_t)(m0 + 2) * DD + o], acc2 * inv);

    // bias (once per m): blocks with chunk==0 && sp==0
    if (chunk == 0 && sp == 0) {
        #pragma unroll
        for (int j = 0; j < 3; ++j) {
            const int m = m0 + j;
            atomicAdd(&out[(size_t)m * DD + tid], bfold[tid] * (Sg[m] * inv) + b_dc[tid]);
        }
    }
}

// ---------------------------------------------------------------------------
extern "C" void kernel_launch(void* const* d_in, const int* in_sizes, int n_in,
                              void* d_out, int out_size, void* d_ws, size_t ws_size,
                              hipStream_t stream) {
    // setup_inputs order: imgs, i_features, p_motions, W_emb, b_emb, W_dc, b_dc
    const float* i_features = (const float*)d_in[1];
    const float* p_motions  = (const float*)d_in[2];
    const float* W_emb      = (const float*)d_in[3];
    const float* b_emb      = (const float*)d_in[4];
    const float* W_dc       = (const float*)d_in[5];
    const float* b_dc       = (const float*)d_in[6];
    float* out = (float*)d_out;

    float* ws = (float*)d_ws;
    float* Ag    = ws;                                   // 48*4096 = 196608
    float* Sg    = Ag + (size_t)M_TOTAL * HW;            // 48 (pad 64)
    float* WT    = Sg + 64;                              // 65536
    float* bfold = WT + 65536;                           // 256
    // total ~1.05 MB

    k_pre<<<M_TOTAL + DD, 256, 0, stream>>>(p_motions, W_emb, b_emb, W_dc,
                                            Ag, Sg, WT, bfold, out);
    dim3 g2(16, 8, NSP);
    k_gather_out<<<g2, 256, 0, stream>>>(i_features, Ag, Sg, WT, bfold, b_dc, out);
}